// Round 18
// baseline (857.737 us; speedup 1.0000x reference)
//
#include <hip/hip_runtime.h>
#include <hip/hip_bf16.h>

using f32x4  = __attribute__((ext_vector_type(4))) float;
using bf16x8 = __attribute__((ext_vector_type(8))) short;
using short8 = __attribute__((ext_vector_type(8))) short;
using s16x4  = __attribute__((ext_vector_type(4))) short;

#define DEVINL __device__ __forceinline__

DEVINL short f2bf(float f) {
  unsigned u = __builtin_bit_cast(unsigned, f);
  u += 0x7fffu + ((u >> 16) & 1u);          // RNE
  return (short)(u >> 16);
}
DEVINL float bf2f(short h) {
  return __builtin_bit_cast(float, (unsigned)((unsigned short)h) << 16);
}

// tanh-approx GELU in sigmoid form: 0.5v(1+tanh(u)) == v/(1+exp(-2u))
DEVINL float gelu_fast(float v) {
  float t = __expf(-1.5957691216057308f * (v + 0.044715f * v * v * v));
  return v * __builtin_amdgcn_rcpf(1.0f + t);
}

#define GLDS16(g, l) __builtin_amdgcn_global_load_lds( \
    (const __attribute__((address_space(1))) void*)(g), \
    (__attribute__((address_space(3))) void*)(l), 16, 0, 0)

// ---------------------------------------------------------------- transpose
__global__ __launch_bounds__(256)
void transpose_bf16(const float* __restrict__ in, short* __restrict__ out, int R, int C) {
  int idx = blockIdx.x * 256 + threadIdx.x;
  if (idx >= R * C) return;
  int c = idx / R, r = idx % R;
  out[idx] = f2bf(in[(size_t)r * C + c]);
}

// ---------------------------------------------------------------- bias expand
__global__ __launch_bounds__(256)
void bias_expand(const float* __restrict__ rpb, float* __restrict__ BIASF) {
  int idx = blockIdx.x * 256 + threadIdx.x;   // 65536
  int head = idx >> 12, n = (idx >> 6) & 63, m = idx & 63;
  int i1 = n >> 3, j1 = n & 7, i2 = m >> 3, j2 = m & 7;
  BIASF[idx] = rpb[((i1 - i2 + 7) * 15 + (j1 - j2 + 7)) * 16 + head];
}

// ---------------------------------------------------------------- LayerNorm (fp32 in, bf16 out)
template<int REMAP>
__global__ __launch_bounds__(256)
void ln_kernel(const float* __restrict__ X, const float* __restrict__ gamma,
               const float* __restrict__ beta, short* __restrict__ OUT) {
  const int lane = threadIdx.x & 63;
  const int wid  = threadIdx.x >> 6;
  const int t    = blockIdx.x * 4 + wid;
  const float* xp = X + (size_t)t * 512 + lane * 8;
  float4 a = *(const float4*)xp;
  float4 b = *(const float4*)(xp + 4);
  float s = a.x + a.y + a.z + a.w + b.x + b.y + b.z + b.w;
  float q = a.x*a.x + a.y*a.y + a.z*a.z + a.w*a.w
          + b.x*b.x + b.y*b.y + b.z*b.z + b.w*b.w;
#pragma unroll
  for (int d = 1; d < 64; d <<= 1) { s += __shfl_xor(s, d); q += __shfl_xor(q, d); }
  float mean = s * (1.0f / 512.0f);
  float var  = q * (1.0f / 512.0f) - mean * mean;
  float rstd = rsqrtf(var + 1e-5f);
  float4 g0 = *(const float4*)(gamma + lane * 8);
  float4 g1 = *(const float4*)(gamma + lane * 8 + 4);
  float4 b0 = *(const float4*)(beta + lane * 8);
  float4 b1 = *(const float4*)(beta + lane * 8 + 4);
  short8 o;
  o[0] = f2bf((a.x - mean) * rstd * g0.x + b0.x);
  o[1] = f2bf((a.y - mean) * rstd * g0.y + b0.y);
  o[2] = f2bf((a.z - mean) * rstd * g0.z + b0.z);
  o[3] = f2bf((a.w - mean) * rstd * g0.w + b0.w);
  o[4] = f2bf((b.x - mean) * rstd * g1.x + b1.x);
  o[5] = f2bf((b.y - mean) * rstd * g1.y + b1.y);
  o[6] = f2bf((b.z - mean) * rstd * g1.z + b1.z);
  o[7] = f2bf((b.w - mean) * rstd * g1.w + b1.w);
  size_t orow;
  if (REMAP) {
    int bb = t >> 12, l = t & 4095, hh = l >> 6, ww = l & 63;
    int hs = (hh + 60) & 63, ws2 = (ww + 60) & 63;   // (coord - 4) mod 64
    orow = (size_t)(bb * 64 + (hs >> 3) * 8 + (ws2 >> 3)) * 64 + (hs & 7) * 8 + (ws2 & 7);
  } else {
    orow = (size_t)t;
  }
  *(short8*)(OUT + orow * 512 + lane * 8) = o;
}

// ---------------------------------------------------------------- LayerNorm (bf16 in, bf16 out)
__global__ __launch_bounds__(256)
void ln_bf16(const short* __restrict__ X, const float* __restrict__ gamma,
             const float* __restrict__ beta, short* __restrict__ OUT) {
  const int lane = threadIdx.x & 63;
  const int wid  = threadIdx.x >> 6;
  const int t    = blockIdx.x * 4 + wid;
  short8 v = *(const short8*)(X + (size_t)t * 512 + lane * 8);
  float f[8];
#pragma unroll
  for (int k = 0; k < 8; ++k) f[k] = bf2f(v[k]);
  float s = 0.f, q = 0.f;
#pragma unroll
  for (int k = 0; k < 8; ++k) { s += f[k]; q += f[k] * f[k]; }
#pragma unroll
  for (int d = 1; d < 64; d <<= 1) { s += __shfl_xor(s, d); q += __shfl_xor(q, d); }
  float mean = s * (1.0f / 512.0f);
  float var  = q * (1.0f / 512.0f) - mean * mean;
  float rstd = rsqrtf(var + 1e-5f);
  float4 g0 = *(const float4*)(gamma + lane * 8);
  float4 g1 = *(const float4*)(gamma + lane * 8 + 4);
  float4 b0 = *(const float4*)(beta + lane * 8);
  float4 b1 = *(const float4*)(beta + lane * 8 + 4);
  short8 o;
  o[0] = f2bf((f[0] - mean) * rstd * g0.x + b0.x);
  o[1] = f2bf((f[1] - mean) * rstd * g0.y + b0.y);
  o[2] = f2bf((f[2] - mean) * rstd * g0.z + b0.z);
  o[3] = f2bf((f[3] - mean) * rstd * g0.w + b0.w);
  o[4] = f2bf((f[4] - mean) * rstd * g1.x + b1.x);
  o[5] = f2bf((f[5] - mean) * rstd * g1.y + b1.y);
  o[6] = f2bf((f[6] - mean) * rstd * g1.z + b1.z);
  o[7] = f2bf((f[7] - mean) * rstd * g1.w + b1.w);
  *(short8*)(OUT + (size_t)t * 512 + lane * 8) = o;
}

// ---------------------------------------------------------------- attention core
__global__ __launch_bounds__(256)
void attn_core(const short* __restrict__ Q, const short* __restrict__ Kb,
               const short* __restrict__ VT, const float* __restrict__ BIASF,
               short* __restrict__ AOUT) {
  __shared__ short P[4][4096];
  const int tid = threadIdx.x, lane = tid & 63, wid = tid >> 6;
  const int lr = lane & 15, lg = lane >> 4;
  const int gw = blockIdx.x * 4 + wid;
  const int win = gw >> 4, head = gw & 15;
  const int wimg = win & 63, wh = wimg >> 3, ww = wimg & 7;
  const size_t qbase = (size_t)win * 64 * 512 + head * 32;
  short* Pb = P[wid];

  bf16x8 aq[4], bk[4];
#pragma unroll
  for (int tm = 0; tm < 4; ++tm) aq[tm] = *(const bf16x8*)(Q  + qbase + (size_t)(tm * 16 + lr) * 512 + lg * 8);
#pragma unroll
  for (int tn = 0; tn < 4; ++tn) bk[tn] = *(const bf16x8*)(Kb + qbase + (size_t)(tn * 16 + lr) * 512 + lg * 8);
  f32x4 sa[4][4] = {};
#pragma unroll
  for (int tm = 0; tm < 4; ++tm)
#pragma unroll
    for (int tn = 0; tn < 4; ++tn)
      sa[tm][tn] = __builtin_amdgcn_mfma_f32_16x16x32_bf16(aq[tm], bk[tn], sa[tm][tn], 0, 0, 0);

  const float* bias_h = BIASF + head * 4096;
  float inv[4][4];
#pragma unroll
  for (int tm = 0; tm < 4; ++tm) {
#pragma unroll
    for (int e = 0; e < 4; ++e) {
      const int n = tm * 16 + lg * 4 + e;
      const int i1 = n >> 3, j1 = n & 7;
      const int rh1 = (wh == 7) ? 1 + (i1 >> 2) : 0;
      const int rw1 = (ww == 7) ? 1 + (j1 >> 2) : 0;
      float v[4];
      float mx = -3.0e38f;
#pragma unroll
      for (int tn = 0; tn < 4; ++tn) {
        const int m = tn * 16 + lr;
        const int mi = (m >> 3), mj = m & 7;
        const int rh2 = (wh == 7) ? 1 + (mi >> 2) : 0;
        const int rw2 = (ww == 7) ? 1 + (mj >> 2) : 0;
        float val = sa[tm][tn][e] + bias_h[n * 64 + m]
                  + ((rh1 != rh2 || rw1 != rw2) ? -100.0f : 0.0f);
        v[tn] = val;
        mx = fmaxf(mx, val);
      }
#pragma unroll
      for (int d = 1; d < 16; d <<= 1) mx = fmaxf(mx, __shfl_xor(mx, d));
      float sum = 0.f;
#pragma unroll
      for (int tn = 0; tn < 4; ++tn) { v[tn] = __expf(v[tn] - mx); sum += v[tn]; }
#pragma unroll
      for (int d = 1; d < 16; d <<= 1) sum += __shfl_xor(sum, d);
      inv[tm][e] = 1.0f / sum;
      const int sw = (n & 7) << 3;
#pragma unroll
      for (int tn = 0; tn < 4; ++tn) Pb[n * 64 + ((tn * 16 + lr) ^ sw)] = f2bf(v[tn]);
    }
  }
  __syncthreads();

  f32x4 oa[4][2] = {};
  const short* vt = VT + (size_t)win * 32768 + head * 2048;
#pragma unroll
  for (int ks = 0; ks < 2; ++ks) {
    bf16x8 pa[4], bv[2];
#pragma unroll
    for (int tm = 0; tm < 4; ++tm) {
      const int r = tm * 16 + lr;
      pa[tm] = *(const bf16x8*)(Pb + r * 64 + ((ks * 32 + lg * 8) ^ ((r & 7) << 3)));
    }
#pragma unroll
    for (int t2 = 0; t2 < 2; ++t2) bv[t2] = *(const bf16x8*)(vt + (t2 * 16 + lr) * 64 + ks * 32 + lg * 8);
#pragma unroll
    for (int tm = 0; tm < 4; ++tm)
#pragma unroll
      for (int t2 = 0; t2 < 2; ++t2)
        oa[tm][t2] = __builtin_amdgcn_mfma_f32_16x16x32_bf16(pa[tm], bv[t2], oa[tm][t2], 0, 0, 0);
  }
#pragma unroll
  for (int tm = 0; tm < 4; ++tm)
#pragma unroll
    for (int t2 = 0; t2 < 2; ++t2)
#pragma unroll
      for (int e = 0; e < 4; ++e) {
        const int n = tm * 16 + lg * 4 + e;
        AOUT[((size_t)win * 64 + n) * 512 + head * 32 + t2 * 16 + lr] = f2bf(oa[tm][t2][e] * inv[tm][e]);
      }
}

// ---------------------------------------------------------------- 256x128 GEMM, BK=64
// R17 structure (BK=64, 48KB LDS, 2 blocks/CU, 64 VGPR + 64 acc, both-sides
// swizzle, XCD-bijective). Epilogues reworked for traffic:
// EPI 0 (proj): C[tok][out] -> X2B bf16 window-reversed, + x(fp32) residual
// EPI 1 (fc1, swapped): C[h][tok] -> H1[tok][2048] bf16 gelu, packed s16x4
// EPI 2 (fc2): C[tok][out] -> outf fp32 = acc + bias + X2B(bf16) residual
// EPI 3 (qkv, swapped): C[oc][tok] -> Q/K packed s16x4 at [tok][512]; VT scalar
template<int EPI, int K, int NX>
__global__ __launch_bounds__(512, 1)
void gemmBK64(const short* __restrict__ Aa, const short* __restrict__ Bb,
              const float* __restrict__ bias, const float* __restrict__ resid,
              const short* __restrict__ residh,
              float* __restrict__ outf, short* __restrict__ outh) {
  constexpr int NT = K / 64;
  __shared__ short L[24576];   // A bytes [0,32768), B bytes [32768,49152)
  const int tid = threadIdx.x;
  const int lane = tid & 63, wid = tid >> 6;
  const int lr = lane & 15, lg = lane >> 4;
  const int wm = wid >> 1, wn = wid & 1;

  // XCD-aware bijective swizzle (all grids are multiples of 8)
  const int nwg = gridDim.x;
  const int id = blockIdx.x;
  const int id2 = (id & 7) * (nwg >> 3) + (id >> 3);
  const bool swapped = (EPI == 1 || EPI == 3);
  const int mt    = swapped ? (id2 % NX) : (id2 / NX);
  const int ntile = swapped ? (id2 / NX) : (id2 % NX);
  const int m0 = mt * 256, n0 = ntile * 128;

  // staging geometry: instr c -> row c*64 + rr, phys slot tid&7
  const int rr = tid >> 3;                                   // 0..63
  const int ss = ((tid & 7) ^ (rr & 7)) * 8;                 // swizzled source col (elems)
  const short* pA = Aa + (size_t)(m0 + rr) * K + ss;
  const short* pB = Bb + (size_t)(n0 + rr) * K + ss;
  char* Ld = (char*)L + tid * 16;

  // frag read bases (slot = (kk*4+lg)^(lr&7))
  const int xr = lr & 7;
  const char* rA0 = (char*)L + (wm * 64 + lr) * 128 + ((lg ^ xr) << 4);
  const char* rA1 = (char*)L + (wm * 64 + lr) * 128 + (((4 + lg) ^ xr) << 4);
  const char* rB0 = (char*)L + 32768 + (wn * 64 + lr) * 128 + ((lg ^ xr) << 4);
  const char* rB1 = (char*)L + 32768 + (wn * 64 + lr) * 128 + (((4 + lg) ^ xr) << 4);

  f32x4 acc[4][4] = {};
  for (int kt = 0; kt < NT; ++kt) {
    const int ko = kt * 64;
    GLDS16(pA + ko,                    Ld);
    GLDS16(pA + ko + (size_t)64  * K,  Ld + 8192);
    GLDS16(pA + ko + (size_t)128 * K,  Ld + 16384);
    GLDS16(pA + ko + (size_t)192 * K,  Ld + 24576);
    GLDS16(pB + ko,                    Ld + 32768);
    GLDS16(pB + ko + (size_t)64  * K,  Ld + 40960);
    __syncthreads();
    bf16x8 a[4], b[4];
#pragma unroll
    for (int i = 0; i < 4; ++i) a[i] = *(const bf16x8*)(rA0 + i * 2048);
#pragma unroll
    for (int j = 0; j < 4; ++j) b[j] = *(const bf16x8*)(rB0 + j * 2048);
#pragma unroll
    for (int i = 0; i < 4; ++i)
#pragma unroll
      for (int j = 0; j < 4; ++j)
        acc[i][j] = __builtin_amdgcn_mfma_f32_16x16x32_bf16(a[i], b[j], acc[i][j], 0, 0, 0);
#pragma unroll
    for (int i = 0; i < 4; ++i) a[i] = *(const bf16x8*)(rA1 + i * 2048);
#pragma unroll
    for (int j = 0; j < 4; ++j) b[j] = *(const bf16x8*)(rB1 + j * 2048);
#pragma unroll
    for (int i = 0; i < 4; ++i)
#pragma unroll
      for (int j = 0; j < 4; ++j)
        acc[i][j] = __builtin_amdgcn_mfma_f32_16x16x32_bf16(a[i], b[j], acc[i][j], 0, 0, 0);
    __syncthreads();
  }

  // ---- epilogue
  if (EPI == 1) {
    // fc1 swapped: C row = h, col = tok; pack 4 consecutive h
#pragma unroll
    for (int i = 0; i < 4; ++i) {
      const int h0 = m0 + wm * 64 + i * 16 + lg * 4;
      const float4 bi = *(const float4*)(bias + h0);
#pragma unroll
      for (int j = 0; j < 4; ++j) {
        const int tok = n0 + wn * 64 + j * 16 + lr;
        s16x4 o;
        o[0] = f2bf(gelu_fast(acc[i][j][0] + bi.x));
        o[1] = f2bf(gelu_fast(acc[i][j][1] + bi.y));
        o[2] = f2bf(gelu_fast(acc[i][j][2] + bi.z));
        o[3] = f2bf(gelu_fast(acc[i][j][3] + bi.w));
        *(s16x4*)(outh + (size_t)tok * 2048 + h0) = o;
      }
    }
  } else if (EPI == 0) {
    // proj: write X2B bf16 at window-reversed row, + x (fp32) residual
#pragma unroll
    for (int j = 0; j < 4; ++j) {
      const int col = n0 + wn * 64 + j * 16 + lr;
      const float bc = bias[col];
#pragma unroll
      for (int i = 0; i < 4; ++i)
#pragma unroll
        for (int e = 0; e < 4; ++e) {
          const int row = m0 + wm * 64 + i * 16 + lg * 4 + e;
          float v = acc[i][j][e] + bc;
          const int wv = row >> 6, n = row & 63;
          const int bb = wv >> 6, wi = wv & 63;
          const int hs = (wi >> 3) * 8 + (n >> 3), ws2 = (wi & 7) * 8 + (n & 7);
          const int hh = (hs + 4) & 63, wwp = (ws2 + 4) & 63;
          const size_t orow = (size_t)bb * 4096 + hh * 64 + wwp;
          outh[orow * 512 + col] = f2bf(resid[orow * 512 + col] + v);
        }
    }
  } else if (EPI == 2) {
    // fc2: out fp32 = acc + bias + X2B (bf16) residual
#pragma unroll
    for (int j = 0; j < 4; ++j) {
      const int col = n0 + wn * 64 + j * 16 + lr;
      const float bc = bias[col];
#pragma unroll
      for (int i = 0; i < 4; ++i)
#pragma unroll
        for (int e = 0; e < 4; ++e) {
          const int row = m0 + wm * 64 + i * 16 + lg * 4 + e;
          outf[(size_t)row * 512 + col] = acc[i][j][e] + bc + bf2f(residh[(size_t)row * 512 + col]);
        }
    }
  } else {
    // qkv swapped: C row = oc, col = tok. seg uniform per block (m0 mult of 256).
    const int seg = m0 >> 9;
    const float qs = 0.17677669529663687f;
#pragma unroll
    for (int i = 0; i < 4; ++i) {
      const int oc0 = m0 + wm * 64 + i * 16 + lg * 4;
      const float4 bi = *(const float4*)(bias + oc0);
#pragma unroll
      for (int j = 0; j < 4; ++j) {
        const int tok = n0 + wn * 64 + j * 16 + lr;
        if (seg == 0) {
          s16x4 o;
          o[0] = f2bf((acc[i][j][0] + bi.x) * qs);
          o[1] = f2bf((acc[i][j][1] + bi.y) * qs);
          o[2] = f2bf((acc[i][j][2] + bi.z) * qs);
          o[3] = f2bf((acc[i][j][3] + bi.w) * qs);
          *(s16x4*)(outh + (size_t)tok * 512 + oc0) = o;
        } else if (seg == 1) {
          s16x4 o;
          o[0] = f2bf(acc[i][j][0] + bi.x);
          o[1] = f2bf(acc[i][j][1] + bi.y);
          o[2] = f2bf(acc[i][j][2] + bi.z);
          o[3] = f2bf(acc[i][j][3] + bi.w);
          *(s16x4*)(outh + 33554432 + (size_t)tok * 512 + (oc0 - 512)) = o;
        } else {
          const int cc0 = oc0 - 1024;                      // d0 = cc0&31, head = cc0>>5
          short* vbase = outh + 67108864 +
              (size_t)((tok >> 6) * 16 + (cc0 >> 5)) * 2048 + (tok & 63);
          const int d0 = cc0 & 31;
          vbase[(d0 + 0) * 64] = f2bf(acc[i][j][0] + bi.x);
          vbase[(d0 + 1) * 64] = f2bf(acc[i][j][1] + bi.y);
          vbase[(d0 + 2) * 64] = f2bf(acc[i][j][2] + bi.z);
          vbase[(d0 + 3) * 64] = f2bf(acc[i][j][3] + bi.w);
        }
      }
    }
  }
}

// ---------------------------------------------------------------- launch
extern "C" void kernel_launch(void* const* d_in, const int* in_sizes, int n_in,
                              void* d_out, int out_size, void* d_ws, size_t ws_size,
                              hipStream_t stream) {
  (void)in_sizes; (void)n_in; (void)out_size; (void)ws_size;
  const float* x      = (const float*)d_in[0];
  const float* g1     = (const float*)d_in[1];
  const float* b1     = (const float*)d_in[2];
  const float* qkv_w  = (const float*)d_in[3];
  const float* qkv_b  = (const float*)d_in[4];
  const float* proj_w = (const float*)d_in[5];
  const float* proj_b = (const float*)d_in[6];
  const float* rpb    = (const float*)d_in[7];
  const float* g2     = (const float*)d_in[8];
  const float* b2     = (const float*)d_in[9];
  const float* fc1_w  = (const float*)d_in[10];
  const float* fc1_b  = (const float*)d_in[11];
  const float* fc2_w  = (const float*)d_in[12];
  const float* fc2_b  = (const float*)d_in[13];
  float* out = (float*)d_out;
  char* ws = (char*)d_ws;

  short* WQKVT  = (short*)(ws);                 // [1536][512] bf16   1.5MB
  short* WPROJT = (short*)(ws + 1572864);       // [512][512]         0.5MB
  short* WFC1T  = (short*)(ws + 2097152);       // [2048][512]        2MB
  short* WFC2T  = (short*)(ws + 4194304);       // [512][2048]        2MB
  short* X2B    = (short*)(ws + 6291456);       // [65536][512] bf16  64MB
  float* BIASF  = (float*)(ws + 6291456);       // 256KB alias (dead before proj writes X2B)
  short* ATT    = (short*)(ws + 140509184);     // [65536][512] bf16  64MB (X2N reuse)
  short* XW     = (short*)(ws + 207618048);     // [65536][512] bf16  64MB
  short* QB     = (short*)(ws + 274726912);     // Q|K|VT 3x64MB
  short* H1     = XW;                           // [65536][2048] bf16 256MB over XW+QB (dead)
  short* X2N    = ATT;

  transpose_bf16<<<3072, 256, 0, stream>>>(qkv_w,  WQKVT, 512, 1536);
  transpose_bf16<<<1024, 256, 0, stream>>>(proj_w, WPROJT, 512, 512);
  transpose_bf16<<<4096, 256, 0, stream>>>(fc1_w,  WFC1T, 512, 2048);
  transpose_bf16<<<4096, 256, 0, stream>>>(fc2_w,  WFC2T, 2048, 512);
  bias_expand<<<256, 256, 0, stream>>>(rpb, BIASF);

  ln_kernel<1><<<16384, 256, 0, stream>>>(x, g1, b1, XW);
  // qkv SWAPPED: A=WQKVT (6 m-tiles), B=XW (512 n-tiles) -> C[oc][tok]
  gemmBK64<3, 512, 6><<<3072, 512, 0, stream>>>(WQKVT, XW, qkv_b, nullptr, nullptr, nullptr, QB);
  attn_core<<<4096, 256, 0, stream>>>(QB, QB + 33554432, QB + 67108864, BIASF, ATT);
  // proj: A=ATT (256 m-tiles), BT=WPROJT (4 n-tiles) -> X2B bf16 (window-reverse + x resid)
  gemmBK64<0, 512, 4><<<1024, 512, 0, stream>>>(ATT, WPROJT, proj_b, x, nullptr, nullptr, X2B);
  ln_bf16<<<16384, 256, 0, stream>>>(X2B, g2, b2, X2N);
  // fc1 swapped: A=W1T (8 m-tiles), B=X2N (512 n-tiles) -> H1[tok][2048]
  gemmBK64<1, 512, 8><<<4096, 512, 0, stream>>>(WFC1T, X2N, fc1_b, nullptr, nullptr, nullptr, H1);
  // fc2: A=H1 (256 m-tiles), BT=W2T (4 n-tiles) -> out fp32 + bias + X2B resid
  gemmBK64<2, 2048, 4><<<1024, 512, 0, stream>>>(H1, WFC2T, fc2_b, nullptr, X2B, out, nullptr);
}

// Round 19
// 854.680 us; speedup vs baseline: 1.0036x; 1.0036x over previous
//
#include <hip/hip_runtime.h>
#include <hip/hip_bf16.h>

using f32x4  = __attribute__((ext_vector_type(4))) float;
using bf16x8 = __attribute__((ext_vector_type(8))) short;
using short8 = __attribute__((ext_vector_type(8))) short;
using s16x4  = __attribute__((ext_vector_type(4))) short;

#define DEVINL __device__ __forceinline__

DEVINL short f2bf(float f) {
  unsigned u = __builtin_bit_cast(unsigned, f);
  u += 0x7fffu + ((u >> 16) & 1u);          // RNE
  return (short)(u >> 16);
}
DEVINL float bf2f(short h) {
  return __builtin_bit_cast(float, (unsigned)((unsigned short)h) << 16);
}

// tanh-approx GELU in sigmoid form: 0.5v(1+tanh(u)) == v/(1+exp(-2u))
DEVINL float gelu_fast(float v) {
  float t = __expf(-1.5957691216057308f * (v + 0.044715f * v * v * v));
  return v * __builtin_amdgcn_rcpf(1.0f + t);
}

#define GLDS16(g, l) __builtin_amdgcn_global_load_lds( \
    (const __attribute__((address_space(1))) void*)(g), \
    (__attribute__((address_space(3))) void*)(l), 16, 0, 0)

#define SBAR() __builtin_amdgcn_s_barrier()
#define WAITV(n) asm volatile("s_waitcnt vmcnt(" #n ")" ::: "memory")

// ---------------------------------------------------------------- transpose
__global__ __launch_bounds__(256)
void transpose_bf16(const float* __restrict__ in, short* __restrict__ out, int R, int C) {
  int idx = blockIdx.x * 256 + threadIdx.x;
  if (idx >= R * C) return;
  int c = idx / R, r = idx % R;
  out[idx] = f2bf(in[(size_t)r * C + c]);
}

// ---------------------------------------------------------------- bias expand
__global__ __launch_bounds__(256)
void bias_expand(const float* __restrict__ rpb, float* __restrict__ BIASF) {
  int idx = blockIdx.x * 256 + threadIdx.x;   // 65536
  int head = idx >> 12, n = (idx >> 6) & 63, m = idx & 63;
  int i1 = n >> 3, j1 = n & 7, i2 = m >> 3, j2 = m & 7;
  BIASF[idx] = rpb[((i1 - i2 + 7) * 15 + (j1 - j2 + 7)) * 16 + head];
}

// ---------------------------------------------------------------- LayerNorm (fp32 in, bf16 out)
template<int REMAP>
__global__ __launch_bounds__(256)
void ln_kernel(const float* __restrict__ X, const float* __restrict__ gamma,
               const float* __restrict__ beta, short* __restrict__ OUT) {
  const int lane = threadIdx.x & 63;
  const int wid  = threadIdx.x >> 6;
  const int t    = blockIdx.x * 4 + wid;
  const float* xp = X + (size_t)t * 512 + lane * 8;
  float4 a = *(const float4*)xp;
  float4 b = *(const float4*)(xp + 4);
  float s = a.x + a.y + a.z + a.w + b.x + b.y + b.z + b.w;
  float q = a.x*a.x + a.y*a.y + a.z*a.z + a.w*a.w
          + b.x*b.x + b.y*b.y + b.z*b.z + b.w*b.w;
#pragma unroll
  for (int d = 1; d < 64; d <<= 1) { s += __shfl_xor(s, d); q += __shfl_xor(q, d); }
  float mean = s * (1.0f / 512.0f);
  float var  = q * (1.0f / 512.0f) - mean * mean;
  float rstd = rsqrtf(var + 1e-5f);
  float4 g0 = *(const float4*)(gamma + lane * 8);
  float4 g1 = *(const float4*)(gamma + lane * 8 + 4);
  float4 b0 = *(const float4*)(beta + lane * 8);
  float4 b1 = *(const float4*)(beta + lane * 8 + 4);
  short8 o;
  o[0] = f2bf((a.x - mean) * rstd * g0.x + b0.x);
  o[1] = f2bf((a.y - mean) * rstd * g0.y + b0.y);
  o[2] = f2bf((a.z - mean) * rstd * g0.z + b0.z);
  o[3] = f2bf((a.w - mean) * rstd * g0.w + b0.w);
  o[4] = f2bf((b.x - mean) * rstd * g1.x + b1.x);
  o[5] = f2bf((b.y - mean) * rstd * g1.y + b1.y);
  o[6] = f2bf((b.z - mean) * rstd * g1.z + b1.z);
  o[7] = f2bf((b.w - mean) * rstd * g1.w + b1.w);
  size_t orow;
  if (REMAP) {
    int bb = t >> 12, l = t & 4095, hh = l >> 6, ww = l & 63;
    int hs = (hh + 60) & 63, ws2 = (ww + 60) & 63;   // (coord - 4) mod 64
    orow = (size_t)(bb * 64 + (hs >> 3) * 8 + (ws2 >> 3)) * 64 + (hs & 7) * 8 + (ws2 & 7);
  } else {
    orow = (size_t)t;
  }
  *(short8*)(OUT + orow * 512 + lane * 8) = o;
}

// ---------------------------------------------------------------- LayerNorm (bf16 in, bf16 out)
__global__ __launch_bounds__(256)
void ln_bf16(const short* __restrict__ X, const float* __restrict__ gamma,
             const float* __restrict__ beta, short* __restrict__ OUT) {
  const int lane = threadIdx.x & 63;
  const int wid  = threadIdx.x >> 6;
  const int t    = blockIdx.x * 4 + wid;
  short8 v = *(const short8*)(X + (size_t)t * 512 + lane * 8);
  float f[8];
#pragma unroll
  for (int k = 0; k < 8; ++k) f[k] = bf2f(v[k]);
  float s = 0.f, q = 0.f;
#pragma unroll
  for (int k = 0; k < 8; ++k) { s += f[k]; q += f[k] * f[k]; }
#pragma unroll
  for (int d = 1; d < 64; d <<= 1) { s += __shfl_xor(s, d); q += __shfl_xor(q, d); }
  float mean = s * (1.0f / 512.0f);
  float var  = q * (1.0f / 512.0f) - mean * mean;
  float rstd = rsqrtf(var + 1e-5f);
  float4 g0 = *(const float4*)(gamma + lane * 8);
  float4 g1 = *(const float4*)(gamma + lane * 8 + 4);
  float4 b0 = *(const float4*)(beta + lane * 8);
  float4 b1 = *(const float4*)(beta + lane * 8 + 4);
  short8 o;
  o[0] = f2bf((f[0] - mean) * rstd * g0.x + b0.x);
  o[1] = f2bf((f[1] - mean) * rstd * g0.y + b0.y);
  o[2] = f2bf((f[2] - mean) * rstd * g0.z + b0.z);
  o[3] = f2bf((f[3] - mean) * rstd * g0.w + b0.w);
  o[4] = f2bf((f[4] - mean) * rstd * g1.x + b1.x);
  o[5] = f2bf((f[5] - mean) * rstd * g1.y + b1.y);
  o[6] = f2bf((f[6] - mean) * rstd * g1.z + b1.z);
  o[7] = f2bf((f[7] - mean) * rstd * g1.w + b1.w);
  *(short8*)(OUT + (size_t)t * 512 + lane * 8) = o;
}

// ---------------------------------------------------------------- attention core
__global__ __launch_bounds__(256)
void attn_core(const short* __restrict__ Q, const short* __restrict__ Kb,
               const short* __restrict__ VT, const float* __restrict__ BIASF,
               short* __restrict__ AOUT) {
  __shared__ short P[4][4096];
  const int tid = threadIdx.x, lane = tid & 63, wid = tid >> 6;
  const int lr = lane & 15, lg = lane >> 4;
  const int gw = blockIdx.x * 4 + wid;
  const int win = gw >> 4, head = gw & 15;
  const int wimg = win & 63, wh = wimg >> 3, ww = wimg & 7;
  const size_t qbase = (size_t)win * 64 * 512 + head * 32;
  short* Pb = P[wid];

  bf16x8 aq[4], bk[4];
#pragma unroll
  for (int tm = 0; tm < 4; ++tm) aq[tm] = *(const bf16x8*)(Q  + qbase + (size_t)(tm * 16 + lr) * 512 + lg * 8);
#pragma unroll
  for (int tn = 0; tn < 4; ++tn) bk[tn] = *(const bf16x8*)(Kb + qbase + (size_t)(tn * 16 + lr) * 512 + lg * 8);
  f32x4 sa[4][4] = {};
#pragma unroll
  for (int tm = 0; tm < 4; ++tm)
#pragma unroll
    for (int tn = 0; tn < 4; ++tn)
      sa[tm][tn] = __builtin_amdgcn_mfma_f32_16x16x32_bf16(aq[tm], bk[tn], sa[tm][tn], 0, 0, 0);

  const float* bias_h = BIASF + head * 4096;
  float inv[4][4];
#pragma unroll
  for (int tm = 0; tm < 4; ++tm) {
#pragma unroll
    for (int e = 0; e < 4; ++e) {
      const int n = tm * 16 + lg * 4 + e;
      const int i1 = n >> 3, j1 = n & 7;
      const int rh1 = (wh == 7) ? 1 + (i1 >> 2) : 0;
      const int rw1 = (ww == 7) ? 1 + (j1 >> 2) : 0;
      float v[4];
      float mx = -3.0e38f;
#pragma unroll
      for (int tn = 0; tn < 4; ++tn) {
        const int m = tn * 16 + lr;
        const int mi = (m >> 3), mj = m & 7;
        const int rh2 = (wh == 7) ? 1 + (mi >> 2) : 0;
        const int rw2 = (ww == 7) ? 1 + (mj >> 2) : 0;
        float val = sa[tm][tn][e] + bias_h[n * 64 + m]
                  + ((rh1 != rh2 || rw1 != rw2) ? -100.0f : 0.0f);
        v[tn] = val;
        mx = fmaxf(mx, val);
      }
#pragma unroll
      for (int d = 1; d < 16; d <<= 1) mx = fmaxf(mx, __shfl_xor(mx, d));
      float sum = 0.f;
#pragma unroll
      for (int tn = 0; tn < 4; ++tn) { v[tn] = __expf(v[tn] - mx); sum += v[tn]; }
#pragma unroll
      for (int d = 1; d < 16; d <<= 1) sum += __shfl_xor(sum, d);
      inv[tm][e] = 1.0f / sum;
      const int sw = (n & 7) << 3;
#pragma unroll
      for (int tn = 0; tn < 4; ++tn) Pb[n * 64 + ((tn * 16 + lr) ^ sw)] = f2bf(v[tn]);
    }
  }
  __syncthreads();

  f32x4 oa[4][2] = {};
  const short* vt = VT + (size_t)win * 32768 + head * 2048;
#pragma unroll
  for (int ks = 0; ks < 2; ++ks) {
    bf16x8 pa[4], bv[2];
#pragma unroll
    for (int tm = 0; tm < 4; ++tm) {
      const int r = tm * 16 + lr;
      pa[tm] = *(const bf16x8*)(Pb + r * 64 + ((ks * 32 + lg * 8) ^ ((r & 7) << 3)));
    }
#pragma unroll
    for (int t2 = 0; t2 < 2; ++t2) bv[t2] = *(const bf16x8*)(vt + (t2 * 16 + lr) * 64 + ks * 32 + lg * 8);
#pragma unroll
    for (int tm = 0; tm < 4; ++tm)
#pragma unroll
      for (int t2 = 0; t2 < 2; ++t2)
        oa[tm][t2] = __builtin_amdgcn_mfma_f32_16x16x32_bf16(pa[tm], bv[t2], oa[tm][t2], 0, 0, 0);
  }
#pragma unroll
  for (int tm = 0; tm < 4; ++tm)
#pragma unroll
    for (int t2 = 0; t2 < 2; ++t2)
#pragma unroll
      for (int e = 0; e < 4; ++e) {
        const int n = tm * 16 + lg * 4 + e;
        AOUT[((size_t)win * 64 + n) * 512 + head * 32 + t2 * 16 + lr] = f2bf(oa[tm][t2][e] * inv[tm][e]);
      }
}

// ---------------------------------------------------------------- 256x128 GEMM, 8-phase counted-vmcnt
// T3+T4 per the verified 8-phase template: phase = one k-half (32 cols).
// 4-slot LDS ring (slot 24KB: A 256x32 | B 128x32; 96KB total, 1 blk/CU — the
// schedule, not TLP, provides overlap per m201). Per phase:
//   {8 ds_read_b128 -> stage slot h+3 (3 gloads) -> setprio + 16 MFMA ->
//    WAITV(6|3|0) -> SBAR -> sched_barrier}.
// WAITV(6) leaves slots h+2,h+3 in flight; slot h+1 landed before its phase.
// Stage targets slot (h-1)&3 whose readers are behind the previous barrier.
// Swizzle involution: phys16B-slot = logical ^ ((row>>1)&3), both sides; 2-way free.
// 8 waves (4m x 2n), wave tile 64x64.
template<int EPI, int K, int NX>
__global__ __launch_bounds__(512, 1)
void gemm8p(const short* __restrict__ Aa, const short* __restrict__ Bb,
            const float* __restrict__ bias, const float* __restrict__ resid,
            const short* __restrict__ residh,
            float* __restrict__ outf, short* __restrict__ outh) {
  constexpr int P = K / 32;               // phases (k-halves)
  __shared__ short L[49152];              // 4 slots x 24576 B
  const int tid = threadIdx.x;
  const int lane = tid & 63, wid = tid >> 6;
  const int lr = lane & 15, lg = lane >> 4;
  const int wm = wid >> 1, wn = wid & 1;

  // XCD-aware bijective swizzle (all grids are multiples of 8)
  const int nwg = gridDim.x;
  const int id = blockIdx.x;
  const int id2 = (id & 7) * (nwg >> 3) + (id >> 3);
  const bool swapped = (EPI == 1 || EPI == 3);
  const int mt    = swapped ? (id2 % NX) : (id2 / NX);
  const int ntile = swapped ? (id2 / NX) : (id2 % NX);
  const int m0 = mt * 256, n0 = ntile * 128;

  // staging: thread -> row tid>>2 (0..127), phys 16B-slot tid&3.
  // source logical group = (tid&3) ^ ((tid>>3)&3)  [involution]
  const int scol = (((tid & 3) ^ ((tid >> 3) & 3)) * 8);
  const short* pA0 = Aa + (size_t)(m0 + (tid >> 2)) * K + scol;
  const short* pA1 = Aa + (size_t)(m0 + 128 + (tid >> 2)) * K + scol;
  const short* pB0 = Bb + (size_t)(n0 + (tid >> 2)) * K + scol;
  char* Ld = (char*)L + tid * 16;         // linear dest within slot

  auto stage = [&](int h) {               // stage k-half h into slot h&3
    char* s = Ld + (h & 3) * 24576;
    GLDS16(pA0 + h * 32, s);
    GLDS16(pA1 + h * 32, s + 8192);
    GLDS16(pB0 + h * 32, s + 16384);
  };

  // frag read offsets (phys slot = lg ^ ((lr>>1)&3), thread-constant)
  const int xr2 = (lr >> 1) & 3;
  const int rAoff = (wm * 64 + lr) * 64 + ((lg ^ xr2) << 4);
  const int rBoff = 16384 + (wn * 64 + lr) * 64 + ((lg ^ xr2) << 4);

  f32x4 acc[4][4] = {};
  stage(0); stage(1); stage(2);
  WAITV(6);            // slot 0 landed; 1,2 in flight
  SBAR();
  __builtin_amdgcn_sched_barrier(0);

#define PHASE(S) do { \
    const int h = p + (S); \
    const char* Ls = (char*)L + (S) * 24576; \
    bf16x8 a0 = *(const bf16x8*)(Ls + rAoff + 0 * 1024); \
    bf16x8 a1 = *(const bf16x8*)(Ls + rAoff + 1 * 1024); \
    bf16x8 a2 = *(const bf16x8*)(Ls + rAoff + 2 * 1024); \
    bf16x8 a3 = *(const bf16x8*)(Ls + rAoff + 3 * 1024); \
    bf16x8 b0 = *(const bf16x8*)(Ls + rBoff + 0 * 1024); \
    bf16x8 b1 = *(const bf16x8*)(Ls + rBoff + 1 * 1024); \
    bf16x8 b2 = *(const bf16x8*)(Ls + rBoff + 2 * 1024); \
    bf16x8 b3 = *(const bf16x8*)(Ls + rBoff + 3 * 1024); \
    if (h + 3 < P) stage(h + 3); \
    __builtin_amdgcn_s_setprio(1); \
    acc[0][0] = __builtin_amdgcn_mfma_f32_16x16x32_bf16(a0, b0, acc[0][0], 0, 0, 0); \
    acc[0][1] = __builtin_amdgcn_mfma_f32_16x16x32_bf16(a0, b1, acc[0][1], 0, 0, 0); \
    acc[0][2] = __builtin_amdgcn_mfma_f32_16x16x32_bf16(a0, b2, acc[0][2], 0, 0, 0); \
    acc[0][3] = __builtin_amdgcn_mfma_f32_16x16x32_bf16(a0, b3, acc[0][3], 0, 0, 0); \
    acc[1][0] = __builtin_amdgcn_mfma_f32_16x16x32_bf16(a1, b0, acc[1][0], 0, 0, 0); \
    acc[1][1] = __builtin_amdgcn_mfma_f32_16x16x32_bf16(a1, b1, acc[1][1], 0, 0, 0); \
    acc[1][2] = __builtin_amdgcn_mfma_f32_16x16x32_bf16(a1, b2, acc[1][2], 0, 0, 0); \
    acc[1][3] = __builtin_amdgcn_mfma_f32_16x16x32_bf16(a1, b3, acc[1][3], 0, 0, 0); \
    acc[2][0] = __builtin_amdgcn_mfma_f32_16x16x32_bf16(a2, b0, acc[2][0], 0, 0, 0); \
    acc[2][1] = __builtin_amdgcn_mfma_f32_16x16x32_bf16(a2, b1, acc[2][1], 0, 0, 0); \
    acc[2][2] = __builtin_amdgcn_mfma_f32_16x16x32_bf16(a2, b2, acc[2][2], 0, 0, 0); \
    acc[2][3] = __builtin_amdgcn_mfma_f32_16x16x32_bf16(a2, b3, acc[2][3], 0, 0, 0); \
    acc[3][0] = __builtin_amdgcn_mfma_f32_16x16x32_bf16(a3, b0, acc[3][0], 0, 0, 0); \
    acc[3][1] = __builtin_amdgcn_mfma_f32_16x16x32_bf16(a3, b1, acc[3][1], 0, 0, 0); \
    acc[3][2] = __builtin_amdgcn_mfma_f32_16x16x32_bf16(a3, b2, acc[3][2], 0, 0, 0); \
    acc[3][3] = __builtin_amdgcn_mfma_f32_16x16x32_bf16(a3, b3, acc[3][3], 0, 0, 0); \
    __builtin_amdgcn_s_setprio(0); \
    if (h < P - 3)       { WAITV(6); } \
    else if (h == P - 3) { WAITV(3); } \
    else                 { WAITV(0); } \
    SBAR(); \
    __builtin_amdgcn_sched_barrier(0); \
  } while (0)

  for (int p = 0; p < P; p += 4) {
    PHASE(0); PHASE(1); PHASE(2); PHASE(3);
  }
#undef PHASE

  // ---- epilogue (R18 set)
  if (EPI == 1) {
#pragma unroll
    for (int i = 0; i < 4; ++i) {
      const int h0 = m0 + wm * 64 + i * 16 + lg * 4;
      const float4 bi = *(const float4*)(bias + h0);
#pragma unroll
      for (int j = 0; j < 4; ++j) {
        const int tok = n0 + wn * 64 + j * 16 + lr;
        s16x4 o;
        o[0] = f2bf(gelu_fast(acc[i][j][0] + bi.x));
        o[1] = f2bf(gelu_fast(acc[i][j][1] + bi.y));
        o[2] = f2bf(gelu_fast(acc[i][j][2] + bi.z));
        o[3] = f2bf(gelu_fast(acc[i][j][3] + bi.w));
        *(s16x4*)(outh + (size_t)tok * 2048 + h0) = o;
      }
    }
  } else if (EPI == 0) {
#pragma unroll
    for (int j = 0; j < 4; ++j) {
      const int col = n0 + wn * 64 + j * 16 + lr;
      const float bc = bias[col];
#pragma unroll
      for (int i = 0; i < 4; ++i)
#pragma unroll
        for (int e = 0; e < 4; ++e) {
          const int row = m0 + wm * 64 + i * 16 + lg * 4 + e;
          float v = acc[i][j][e] + bc;
          const int wv = row >> 6, n = row & 63;
          const int bb = wv >> 6, wi = wv & 63;
          const int hs = (wi >> 3) * 8 + (n >> 3), ws2 = (wi & 7) * 8 + (n & 7);
          const int hh = (hs + 4) & 63, wwp = (ws2 + 4) & 63;
          const size_t orow = (size_t)bb * 4096 + hh * 64 + wwp;
          outh[orow * 512 + col] = f2bf(resid[orow * 512 + col] + v);
        }
    }
  } else if (EPI == 2) {
#pragma unroll
    for (int j = 0; j < 4; ++j) {
      const int col = n0 + wn * 64 + j * 16 + lr;
      const float bc = bias[col];
#pragma unroll
      for (int i = 0; i < 4; ++i)
#pragma unroll
        for (int e = 0; e < 4; ++e) {
          const int row = m0 + wm * 64 + i * 16 + lg * 4 + e;
          outf[(size_t)row * 512 + col] = acc[i][j][e] + bc + bf2f(residh[(size_t)row * 512 + col]);
        }
    }
  } else {
    const int seg = m0 >> 9;
    const float qs = 0.17677669529663687f;
#pragma unroll
    for (int i = 0; i < 4; ++i) {
      const int oc0 = m0 + wm * 64 + i * 16 + lg * 4;
      const float4 bi = *(const float4*)(bias + oc0);
#pragma unroll
      for (int j = 0; j < 4; ++j) {
        const int tok = n0 + wn * 64 + j * 16 + lr;
        if (seg == 0) {
          s16x4 o;
          o[0] = f2bf((acc[i][j][0] + bi.x) * qs);
          o[1] = f2bf((acc[i][j][1] + bi.y) * qs);
          o[2] = f2bf((acc[i][j][2] + bi.z) * qs);
          o[3] = f2bf((acc[i][j][3] + bi.w) * qs);
          *(s16x4*)(outh + (size_t)tok * 512 + oc0) = o;
        } else if (seg == 1) {
          s16x4 o;
          o[0] = f2bf(acc[i][j][0] + bi.x);
          o[1] = f2bf(acc[i][j][1] + bi.y);
          o[2] = f2bf(acc[i][j][2] + bi.z);
          o[3] = f2bf(acc[i][j][3] + bi.w);
          *(s16x4*)(outh + 33554432 + (size_t)tok * 512 + (oc0 - 512)) = o;
        } else {
          const int cc0 = oc0 - 1024;
          short* vbase = outh + 67108864 +
              (size_t)((tok >> 6) * 16 + (cc0 >> 5)) * 2048 + (tok & 63);
          const int d0 = cc0 & 31;
          vbase[(d0 + 0) * 64] = f2bf(acc[i][j][0] + bi.x);
          vbase[(d0 + 1) * 64] = f2bf(acc[i][j][1] + bi.y);
          vbase[(d0 + 2) * 64] = f2bf(acc[i][j][2] + bi.z);
          vbase[(d0 + 3) * 64] = f2bf(acc[i][j][3] + bi.w);
        }
      }
    }
  }
}

// ---------------------------------------------------------------- launch
extern "C" void kernel_launch(void* const* d_in, const int* in_sizes, int n_in,
                              void* d_out, int out_size, void* d_ws, size_t ws_size,
                              hipStream_t stream) {
  (void)in_sizes; (void)n_in; (void)out_size; (void)ws_size;
  const float* x      = (const float*)d_in[0];
  const float* g1     = (const float*)d_in[1];
  const float* b1     = (const float*)d_in[2];
  const float* qkv_w  = (const float*)d_in[3];
  const float* qkv_b  = (const float*)d_in[4];
  const float* proj_w = (const float*)d_in[5];
  const float* proj_b = (const float*)d_in[6];
  const float* rpb    = (const float*)d_in[7];
  const float* g2     = (const float*)d_in[8];
  const float* b2     = (const float*)d_in[9];
  const float* fc1_w  = (const float*)d_in[10];
  const float* fc1_b  = (const float*)d_in[11];
  const float* fc2_w  = (const float*)d_in[12];
  const float* fc2_b  = (const float*)d_in[13];
  float* out = (float*)d_out;
  char* ws = (char*)d_ws;

  short* WQKVT  = (short*)(ws);                 // [1536][512] bf16   1.5MB
  short* WPROJT = (short*)(ws + 1572864);       // [512][512]         0.5MB
  short* WFC1T  = (short*)(ws + 2097152);       // [2048][512]        2MB
  short* WFC2T  = (short*)(ws + 4194304);       // [512][2048]        2MB
  short* X2B    = (short*)(ws + 6291456);       // [65536][512] bf16  64MB
  float* BIASF  = (float*)(ws + 6291456);       // 256KB alias (dead before proj writes X2B)
  short* ATT    = (short*)(ws + 140509184);     // [65536][512] bf16  64MB (X2N reuse)
  short* XW     = (short*)(ws + 207618048);     // [65536][512] bf16  64MB
  short* QB     = (short*)(ws + 274726912);     // Q|K|VT 3x64MB
  short* H1     = XW;                           // [65536][2048] bf16 256MB over XW+QB (dead)
  short* X2N    = ATT;

  transpose_bf16<<<3072, 256, 0, stream>>>(qkv_w,  WQKVT, 512, 1536);
  transpose_bf16<<<1024, 256, 0, stream>>>(proj_w, WPROJT, 512, 512);
  transpose_bf16<<<4096, 256, 0, stream>>>(fc1_w,  WFC1T, 512, 2048);
  transpose_bf16<<<4096, 256, 0, stream>>>(fc2_w,  WFC2T, 2048, 512);
  bias_expand<<<256, 256, 0, stream>>>(rpb, BIASF);

  ln_kernel<1><<<16384, 256, 0, stream>>>(x, g1, b1, XW);
  // qkv SWAPPED: A=WQKVT (6 m-tiles), B=XW (512 n-tiles) -> C[oc][tok]
  gemm8p<3, 512, 6><<<3072, 512, 0, stream>>>(WQKVT, XW, qkv_b, nullptr, nullptr, nullptr, QB);
  attn_core<<<4096, 256, 0, stream>>>(QB, QB + 33554432, QB + 67108864, BIASF, ATT);
  // proj: A=ATT (256 m-tiles), BT=WPROJT (4 n-tiles) -> X2B bf16 (window-reverse + x resid)
  gemm8p<0, 512, 4><<<1024, 512, 0, stream>>>(ATT, WPROJT, proj_b, x, nullptr, nullptr, X2B);
  ln_bf16<<<16384, 256, 0, stream>>>(X2B, g2, b2, X2N);
  // fc1 swapped: A=W1T (8 m-tiles), B=X2N (512 n-tiles) -> H1[tok][2048]
  gemm8p<1, 512, 8><<<4096, 512, 0, stream>>>(WFC1T, X2N, fc1_b, nullptr, nullptr, nullptr, H1);
  // fc2: A=H1 (256 m-tiles), BT=W2T (4 n-tiles) -> out fp32 + bias + X2B resid
  gemm8p<2, 2048, 4><<<1024, 512, 0, stream>>>(H1, WFC2T, fc2_b, nullptr, X2B, out, nullptr);
}